// Round 8
// baseline (172.766 us; speedup 1.0000x reference)
//
#include <hip/hip_runtime.h>
#include <hip/hip_bf16.h>
#include <math.h>

#define NBULK 62
#define NBLK  258   // 2 norm + 256 psi (32 samples each)

typedef __attribute__((ext_vector_type(8))) short bf8_t;   // 8 x bf16
typedef __attribute__((ext_vector_type(4))) float f4_t;    // 4 x fp32

#define MFMA(a, b, c) __builtin_amdgcn_mfma_f32_16x16x32_bf16((a), (b), (c), 0, 0, 0)

__device__ __forceinline__ unsigned short f2bf(float f) {
    unsigned int u = __float_as_uint(f);
    return (unsigned short)((u + 0x7FFFu + ((u >> 16) & 1u)) >> 16);
}
__device__ __forceinline__ float bf2f(unsigned short h) {
    return __uint_as_float(((unsigned int)h) << 16);
}
__device__ __forceinline__ unsigned int pk2(float lo, float hi) {
    __hip_bfloat162 h = __float22bfloat162_rn(make_float2(lo, hi));   // lo -> low 16
    unsigned int u;
    __builtin_memcpy(&u, &h, 4);
    return u;
}
__device__ __forceinline__ void gload16(const void* g, void* l) {
    __builtin_amdgcn_global_load_lds(
        (const __attribute__((address_space(1))) unsigned int*)g,
        (__attribute__((address_space(3))) unsigned int*)l, 16, 0, 0);
}

// ---- ws layout ----
// floats: [0]=psisum [1]=lsf [2]=lsb ; int [3]=completion counter
// E_fwd fp32[4096] at float 1024 ; E_bwd at float 6144
// bytes: BT (62*16KB, swizzled) at 45056 ; MR at 1060864
#define WS_E_OFF   1024
#define WS_B_OFF   6144
#define WS_BT_OFF  45056
#define WS_MR_OFF  1060864
// swizzled tile element (row n, col k): n*64 + ((k>>3 ^ (n&7))<<3 | (k&7))

extern "C" __global__ __launch_bounds__(256)
void mps_precompute(const float* __restrict__ bulkG,
                    unsigned short* __restrict__ BTg,
                    unsigned short* __restrict__ MRg,
                    float* __restrict__ wsF)
{
    __shared__ unsigned short BTl[8192];
    __shared__ unsigned short MRl[8192];
    const int s = blockIdx.x, tid = threadIdx.x;
    if (s == 0 && tid == 0) {
        wsF[0] = 0.f; wsF[1] = 0.f; wsF[2] = 0.f;
        ((int*)wsF)[3] = 0;
    }
    const float4* src = (const float4*)(bulkG + (size_t)s * 8192);
    for (int c = 0; c < 8; ++c) {
        int idx = tid + c * 256;
        float4 v = src[idx];
        int f  = idx * 4;
        int kk = f >> 7;
        int p  = (f >> 6) & 1;
        int j  = f & 63;
        unsigned short b0 = f2bf(v.x), b1 = f2bf(v.y), b2 = f2bf(v.z), b3 = f2bf(v.w);
        int n = p * 64 + kk;
        int off = n * 64 + (((j >> 3) ^ (n & 7)) << 3) + (j & 7);
        MRl[off + 0] = b0; MRl[off + 1] = b1; MRl[off + 2] = b2; MRl[off + 3] = b3;
        unsigned short bb[4] = {b0, b1, b2, b3};
        #pragma unroll
        for (int t2 = 0; t2 < 4; ++t2) {
            int n2 = p * 64 + j + t2;
            BTl[n2 * 64 + (((kk >> 3) ^ (n2 & 7)) << 3) + (kk & 7)] = bb[t2];
        }
    }
    __syncthreads();
    const uint4* bt4 = (const uint4*)BTl;
    const uint4* mr4 = (const uint4*)MRl;
    uint4* btg = (uint4*)(BTg + (size_t)s * 8192);
    uint4* mrg = (uint4*)(MRg + (size_t)s * 8192);
    for (int c = 0; c < 4; ++c) {
        int idx = tid + c * 256;
        btg[idx] = bt4[idx];
        mrg[idx] = mr4[idx];
    }
}

extern "C" __global__ __launch_bounds__(64, 1)
void mps_main(const int* __restrict__ cfgG, const float* __restrict__ leftG,
              const float* __restrict__ rightG, float* __restrict__ wsF,
              const unsigned short* __restrict__ BTg,
              const unsigned short* __restrict__ MRg,
              float* __restrict__ outG)
{
    extern __shared__ char smem[];
    unsigned short* smem16 = (unsigned short*)smem;
    const int lane = threadIdx.x;     // 64-thread blocks: tid == lane
    const int bid  = blockIdx.x;
    const int quad = lane >> 4;
    const int ln   = lane & 15;
    const int swz  = ln & 7;

    if (bid >= 2) {
        // ===== psi: 1 wave, 32 samples (2 B-tiles), ZERO barriers =====
        unsigned short* Tb0 = smem16;          // 8192 ush
        unsigned short* Tb1 = Tb0 + 8192;      // 8192
        unsigned short* env = Tb1 + 8192;      // 2048 ush (32 rows x 64)

        const int s0 = (bid - 2) * 32;
        unsigned long long SEL[2];
        #pragma unroll
        for (int bt = 0; bt < 2; ++bt) {
            unsigned long long m = 0ull;
            const int* row = cfgG + (size_t)(s0 + bt * 16 + ln) * 64;
            #pragma unroll
            for (int q = 0; q < 16; ++q) {
                int4 v = *(const int4*)(row + q * 4);
                m |= ((unsigned long long)(v.x & 1)) << (q * 4);
                m |= ((unsigned long long)(v.y & 1)) << (q * 4 + 1);
                m |= ((unsigned long long)(v.z & 1)) << (q * 4 + 2);
                m |= ((unsigned long long)(v.w & 1)) << (q * 4 + 3);
            }
            SEL[bt] = m;
        }
        bf8_t Ef[2][2];
        #pragma unroll
        for (int bt = 0; bt < 2; ++bt) {
            const float* lp = leftG + (int)(SEL[bt] & 1ull) * 64;
            bf8_t t0, t1;
            #pragma unroll
            for (int j = 0; j < 8; ++j) {
                t0[j] = (short)f2bf(lp[quad * 8 + j]);
                t1[j] = (short)f2bf(lp[32 + quad * 8 + j]);
            }
            Ef[bt][0] = t0; Ef[bt][1] = t1;
        }
        {   // prefetch tile 0
            const char* g0 = (const char*)BTg;
            #pragma unroll
            for (int c = 0; c < 16; ++c)
                gload16(g0 + c * 1024 + (size_t)lane * 16, (char*)Tb0 + c * 1024);
        }

        for (int t = 0; t < NBULK; ++t) {
            unsigned short* Tl = (t & 1) ? Tb1 : Tb0;
            if (t + 1 < NBULK) {
                const char* gn = (const char*)(BTg + (size_t)(t + 1) * 8192);
                char* l = (char*)((t & 1) ? Tb0 : Tb1);
                #pragma unroll
                for (int c = 0; c < 16; ++c)
                    gload16(gn + c * 1024 + (size_t)lane * 16, l + c * 1024);
                asm volatile("s_waitcnt vmcnt(16)" ::: "memory");   // tile t resident; t+1 in flight
            } else {
                asm volatile("s_waitcnt vmcnt(0)" ::: "memory");
            }
            f4_t a0[2][4], a1[2][4];
            #pragma unroll
            for (int mt = 0; mt < 4; ++mt) {
                const unsigned short* r0 = Tl + (mt * 16 + ln) * 64;
                const unsigned short* r1 = r0 + 4096;
                bf8_t A00 = *(const bf8_t*)(r0 + ((quad       ^ swz) << 3));
                bf8_t A01 = *(const bf8_t*)(r0 + (((4 + quad) ^ swz) << 3));
                bf8_t A10 = *(const bf8_t*)(r1 + ((quad       ^ swz) << 3));
                bf8_t A11 = *(const bf8_t*)(r1 + (((4 + quad) ^ swz) << 3));
                #pragma unroll
                for (int bt = 0; bt < 2; ++bt) {
                    f4_t x = {0.f, 0.f, 0.f, 0.f};
                    x = MFMA(A00, Ef[bt][0], x);
                    x = MFMA(A01, Ef[bt][1], x);
                    a0[bt][mt] = x;
                    f4_t y = {0.f, 0.f, 0.f, 0.f};
                    y = MFMA(A10, Ef[bt][0], y);
                    y = MFMA(A11, Ef[bt][1], y);
                    a1[bt][mt] = y;
                }
            }
            #pragma unroll
            for (int bt = 0; bt < 2; ++bt) {
                const bool bs = ((SEL[bt] >> (t + 1)) & 1ull) != 0ull;
                unsigned short* eb = env + (bt * 16 + ln) * 64;
                const int esw = swz << 3;
                #pragma unroll
                for (int mt = 0; mt < 4; ++mt) {
                    float v0 = bs ? a1[bt][mt][0] : a0[bt][mt][0];
                    float v1 = bs ? a1[bt][mt][1] : a0[bt][mt][1];
                    float v2 = bs ? a1[bt][mt][2] : a0[bt][mt][2];
                    float v3 = bs ? a1[bt][mt][3] : a0[bt][mt][3];
                    uint2 pk; pk.x = pk2(v0, v1); pk.y = pk2(v2, v3);
                    *(uint2*)(eb + ((mt * 16 + quad * 4) ^ esw)) = pk;
                }
                // same-wave DS ordering guarantees RAW
                Ef[bt][0] = *(const bf8_t*)(eb + ((quad * 8)      ^ esw));
                Ef[bt][1] = *(const bf8_t*)(eb + ((quad * 8 + 32) ^ esw));
            }
        }
        {   // epilogue: per-bt quad-partial dot, quad-sum, log; each sample counted once
            float lptot = 0.f;
            #pragma unroll
            for (int bt = 0; bt < 2; ++bt) {
                const unsigned short* eb = env + (bt * 16 + ln) * 64;
                const int esw = swz << 3;
                const int selL = (int)((SEL[bt] >> 63) & 1ull);
                float p = 0.f;
                #pragma unroll
                for (int g2 = 0; g2 < 2; ++g2) {
                    int g = quad * 2 + g2;
                    bf8_t e = *(const bf8_t*)(eb + ((g * 8) ^ esw));
                    #pragma unroll
                    for (int j = 0; j < 8; ++j)
                        p = fmaf(bf2f((unsigned short)e[j]), rightG[(g * 8 + j) * 2 + selL], p);
                }
                p += __shfl_xor(p, 16);
                p += __shfl_xor(p, 32);
                lptot += logf(fmaxf(p * p, 1e-12f));
            }
            lptot += __shfl_xor(lptot, 1); lptot += __shfl_xor(lptot, 2);
            lptot += __shfl_xor(lptot, 4); lptot += __shfl_xor(lptot, 8);
            if (lane == 0) atomicAdd(&wsF[0], lptot);
        }
    } else {
        // ===== norm chain: 1 wave does the whole site update, ZERO barriers =====
        unsigned short* Tb0 = smem16;          // 8192
        unsigned short* Tb1 = Tb0 + 8192;
        unsigned short* E   = Tb1 + 8192;      // 4096 ush, row i swz by i&7
        unsigned short* St  = E + 4096;        // 2p x 4096: St_p[n][i] swz by n&7

        const bool fwd = (bid == 0);
        const unsigned short* srcbase = fwd ? BTg : MRg;
        for (int idx = lane; idx < 4096; idx += 64) {
            int i = idx >> 6, j = idx & 63;
            float v;
            if (fwd) v = leftG[i] * leftG[j] + leftG[64 + i] * leftG[64 + j];
            else     v = rightG[i * 2] * rightG[j * 2] + rightG[i * 2 + 1] * rightG[j * 2 + 1];
            E[i * 64 + (j ^ ((i & 7) << 3))] = f2bf(v);
        }
        {   // prefetch site 0
            const char* g = (const char*)(srcbase + (size_t)(fwd ? 0 : 61) * 8192);
            #pragma unroll
            for (int c = 0; c < 16; ++c)
                gload16(g + c * 1024 + (size_t)lane * 16, (char*)Tb0 + c * 1024);
        }
        float lsum = 0.f, inv = 1.f;

        for (int k = 0; k < 31; ++k) {
            unsigned short* Tl = (k & 1) ? Tb1 : Tb0;
            if (k + 1 < 31) {
                int sn = fwd ? (k + 1) : (61 - (k + 1));
                const char* g = (const char*)(srcbase + (size_t)sn * 8192);
                char* l = (char*)((k & 1) ? Tb0 : Tb1);
                #pragma unroll
                for (int c = 0; c < 16; ++c)
                    gload16(g + c * 1024 + (size_t)lane * 16, l + c * 1024);
                asm volatile("s_waitcnt vmcnt(16)" ::: "memory");
            } else {
                asm volatile("s_waitcnt vmcnt(0)" ::: "memory");
            }
            // M-frags: reused as stage1-B (rows n) AND stage2-A (rows m)
            bf8_t Mf[2][4][2];
            #pragma unroll
            for (int p = 0; p < 2; ++p)
                #pragma unroll
                for (int rt = 0; rt < 4; ++rt) {
                    const unsigned short* rb = Tl + (p * 64 + rt * 16 + ln) * 64;
                    Mf[p][rt][0] = *(const bf8_t*)(rb + ((quad       ^ swz) << 3));
                    Mf[p][rt][1] = *(const bf8_t*)(rb + (((4 + quad) ^ swz) << 3));
                }
            // E-frags (A-operand, k-contig)
            bf8_t Ea[4][2];
            #pragma unroll
            for (int it = 0; it < 4; ++it) {
                const unsigned short* er = E + (it * 16 + ln) * 64;
                Ea[it][0] = *(const bf8_t*)(er + ((quad * 8)      ^ (swz << 3)));
                Ea[it][1] = *(const bf8_t*)(er + ((quad * 8 + 32) ^ (swz << 3)));
            }
            // stage1: S_p = E @ M_p -> St_p[n][i] (transposed, b64 packs)
            #pragma unroll
            for (int p = 0; p < 2; ++p)
                #pragma unroll
                for (int nt = 0; nt < 4; ++nt) {
                    int n2 = nt * 16 + ln;
                    unsigned short* sb = St + p * 4096 + n2 * 64;
                    #pragma unroll
                    for (int it = 0; it < 4; ++it) {
                        f4_t x = {0.f, 0.f, 0.f, 0.f};
                        x = MFMA(Ea[it][0], Mf[p][nt][0], x);
                        x = MFMA(Ea[it][1], Mf[p][nt][1], x);
                        uint2 pk; pk.x = pk2(x[0], x[1]); pk.y = pk2(x[2], x[3]);
                        *(uint2*)(sb + ((it * 16 + quad * 4) ^ ((n2 & 7) << 3))) = pk;
                    }
                }
            // stage2 B-frags from St (same-wave RAW: DS pipe ordered)
            bf8_t Sf[2][4][2];
            #pragma unroll
            for (int p = 0; p < 2; ++p)
                #pragma unroll
                for (int ni = 0; ni < 4; ++ni) {
                    const unsigned short* br = St + p * 4096 + (ni * 16 + ln) * 64;
                    Sf[p][ni][0] = *(const bf8_t*)(br + ((quad * 8)      ^ (swz << 3)));
                    Sf[p][ni][1] = *(const bf8_t*)(br + ((quad * 8 + 32) ^ (swz << 3)));
                }
            // stage2: E' = sum_p M_p^T S_p, scaled by prev-site inv; write E'^T (symmetric)
            float mx = 0.f;
            #pragma unroll
            for (int mt = 0; mt < 4; ++mt)
                #pragma unroll
                for (int nt2 = 0; nt2 < 4; ++nt2) {
                    f4_t x = {0.f, 0.f, 0.f, 0.f};
                    #pragma unroll
                    for (int p = 0; p < 2; ++p) {
                        x = MFMA(Mf[p][mt][0], Sf[p][nt2][0], x);
                        x = MFMA(Mf[p][mt][1], Sf[p][nt2][1], x);
                    }
                    float v0 = x[0] * inv, v1 = x[1] * inv, v2 = x[2] * inv, v3 = x[3] * inv;
                    mx = fmaxf(mx, fmaxf(fmaxf(fabsf(v0), fabsf(v1)), fmaxf(fabsf(v2), fabsf(v3))));
                    int n2 = nt2 * 16 + ln;
                    uint2 pk; pk.x = pk2(v0, v1); pk.y = pk2(v2, v3);
                    *(uint2*)(E + n2 * 64 + ((mt * 16 + quad * 4) ^ ((n2 & 7) << 3))) = pk;
                }
            mx = fmaxf(mx, __shfl_xor(mx, 1));  mx = fmaxf(mx, __shfl_xor(mx, 2));
            mx = fmaxf(mx, __shfl_xor(mx, 4));  mx = fmaxf(mx, __shfl_xor(mx, 8));
            mx = fmaxf(mx, __shfl_xor(mx, 16)); mx = fmaxf(mx, __shfl_xor(mx, 32));
            if (k < 30) {
                float sc = fmaxf(mx, 1e-30f);
                inv = 1.f / sc;
                lsum += logf(sc);     // uniform across lanes
            }
        }
        float* dst = wsF + (fwd ? WS_E_OFF : WS_B_OFF);
        for (int idx = lane; idx < 4096; idx += 64) {
            int i = idx >> 6, j = idx & 63;
            dst[idx] = bf2f(E[i * 64 + (j ^ ((i & 7) << 3))]);
        }
        if (lane == 0) wsF[fwd ? 1 : 2] = lsum;
    }

    // ===== fused finalize: last block computes the output (single-wave blocks) =====
    __threadfence();                  // release
    int last = 0;
    if (lane == 0) {
        int old = atomicAdd((int*)wsF + 3, 1);
        last = (old == NBLK - 1) ? 1 : 0;
    }
    last = __shfl(last, 0);
    if (last) {
        __threadfence();              // acquire
        const float4* Ew = (const float4*)(wsF + WS_E_OFF);
        const float4* Bw = (const float4*)(wsF + WS_B_OFF);
        float a = 0.f;
        #pragma unroll
        for (int c = 0; c < 16; ++c) {
            int idx = lane + c * 64;
            float4 e = Ew[idx], b = Bw[idx];
            a += e.x * b.x + e.y * b.y + e.z * b.z + e.w * b.w;
        }
        a += __shfl_xor(a, 1);  a += __shfl_xor(a, 2);
        a += __shfl_xor(a, 4);  a += __shfl_xor(a, 8);
        a += __shfl_xor(a, 16); a += __shfl_xor(a, 32);
        if (lane == 0) {
            float z = fmaxf(a, 1e-30f);
            float log_z = logf(z) + wsF[1] + wsF[2];
            outG[0] = log_z - wsF[0] * (1.0f / 8192.0f);
        }
    }
}

extern "C" void kernel_launch(void* const* d_in, const int* in_sizes, int n_in,
                              void* d_out, int out_size, void* d_ws, size_t ws_size,
                              hipStream_t stream)
{
    const int*   cfg   = (const int*)d_in[0];    // (8192, 64) int32
    const float* left  = (const float*)d_in[1];  // (2, 64)
    const float* bulk  = (const float*)d_in[2];  // (62, 64, 2, 64)
    const float* right = (const float*)d_in[3];  // (64, 2)
    float* wsF = (float*)d_ws;
    unsigned short* BTg = (unsigned short*)((char*)d_ws + WS_BT_OFF);
    unsigned short* MRg = (unsigned short*)((char*)d_ws + WS_MR_OFF);

    mps_precompute<<<dim3(62), dim3(256), 0, stream>>>(bulk, BTg, MRg, wsF);
    // blocks 0,1 = norm chains (1 wave each); 2..257 = psi (1 wave, 32 samples each)
    mps_main<<<dim3(NBLK), dim3(64), 57344, stream>>>(cfg, left, right, wsF, BTg, MRg, (float*)d_out);
}